// Round 9
// baseline (217.349 us; speedup 1.0000x reference)
//
#include <hip/hip_runtime.h>

// BagOfWords: input [1024, 512] int32 tokens in [0, 50257).
// Output [1024, 50256] float32: per-row histogram, vocab bin 0 dropped.
//
// R12: memset-zero + half-row sparse winner kernel (clean-window rerun of
// the R11 model discriminator).
//
// R8 ran on a degraded window: the harness poison fills -- the in-window
// calibrator -- measured 153-158 us / 5.3 TB/s vs 122-131 us / 6.6-6.8 TB/s
// in ALL prior rounds. Fill-rate-normalized R8 = 217 x (123/154) ~= 173 us,
// i.e. Model A's win band (rocclr-fill + sparse beats every fused design),
// while raw 217 reads as regression. Unresolved; rerunning.
//
// Changes vs R8's sparse kernel: 2048 half-row blocks (8/CU, 32 waves)
// instead of 1024 row blocks (4/CU) -- R6 showed 4 blocks/CU cannot cover
// serial phases; this halves the per-block barrier chain (7 chunks, not 13)
// and doubles CU parallelism. Logic otherwise the verified R3/R11 winner
// trick: LDS atomicAdd returning 0 elects the bin owner; owner reads the
// final count after an lgkm-only barrier, issues ONE plain dword store
// (lands in MALL lines just dirtied by the memset -> no cold-line RMW),
// re-zeros its bin.
//
// Decision rule (pre-committed): normal window + 172-184 -> Model A, keep
// iterating; normal window + 192-200 -> Model B, declare roofline next
// round (205.8 MB mandatory writes / 6.7 TB/s issue ceiling = 30.7 us;
// the rest of dur_us is harness reset cost).

#define BATCH 1024
#define SEQ 512
#define VOCAB 50257
#define OUT_COLS (VOCAB - 1)   // 50256
#define CHUNK 4096
#define NCHUNK 13              // chunk 12 covers bins 49152..50255 (real max)
#define BLOCK 256

// LDS-only barrier: waits ds ops (lgkmcnt) but does NOT drain global stores.
#define LDS_BAR()                                              \
    do {                                                       \
        asm volatile("s_waitcnt lgkmcnt(0)" ::: "memory");     \
        __builtin_amdgcn_s_barrier();                          \
        asm volatile("" ::: "memory");                         \
    } while (0)

__global__ __launch_bounds__(BLOCK) void bow_sparse_half_kernel(
    const int* __restrict__ tokens, float* __restrict__ out) {
    __shared__ unsigned int hist[CHUNK];  // 16 KB -> 8 blocks/CU

    const int t = threadIdx.x;
    const int b = blockIdx.x >> 1;        // row
    const int h = blockIdx.x & 1;         // chunk-range half
    const int cbeg = h ? 7 : 0;
    const int cend = h ? NCHUNK : 7;

    // Zero the 4096-bin chunk histogram once.
    const uint4 z4 = make_uint4(0u, 0u, 0u, 0u);
    #pragma unroll
    for (int k = 0; k < 4; ++k)
        *(uint4*)&hist[t * 4 + k * (BLOCK * 4)] = z4;

    // This row's 512 tokens, int2 per thread, live across all chunks.
    const int2 tk = ((const int2*)(tokens + (size_t)b * SEQ))[t];
    const unsigned int cx = (unsigned int)(tk.x - 1);  // tok==0 -> 0xFFFFFFFF
    const unsigned int cy = (unsigned int)(tk.y - 1);

    float* orow = out + (size_t)b * OUT_COLS;

    LDS_BAR();  // zeros visible

    for (int c = cbeg; c < cend; ++c) {
        const unsigned int c0 = (unsigned int)c * CHUNK;

        // Accumulate; atomicAdd returning 0 elects this thread bin owner.
        const unsigned int rx = cx - c0;
        const unsigned int ry = cy - c0;
        bool wx = false, wy = false;
        if (rx < CHUNK) wx = (atomicAdd(&hist[rx], 1u) == 0u);
        if (ry < CHUNK) wy = (atomicAdd(&hist[ry], 1u) == 0u);

        LDS_BAR();  // all adds for this chunk complete

        // Owners: read final count, one plain dword store, re-zero own bin.
        // Max real bin = 50255 < OUT_COLS, so no tail bound needed.
        if (wx) {
            const unsigned int cnt = hist[rx];
            orow[c0 + rx] = (float)cnt;
            hist[rx] = 0u;
        }
        if (wy) {
            const unsigned int cnt = hist[ry];
            orow[c0 + ry] = (float)cnt;
            hist[ry] = 0u;
        }

        LDS_BAR();  // re-zeros visible before next chunk's adds
    }
}

extern "C" void kernel_launch(void* const* d_in, const int* in_sizes, int n_in,
                              void* d_out, int out_size, void* d_ws, size_t ws_size,
                              hipStream_t stream) {
    const int* tokens = (const int*)d_in[0];
    float* out = (float*)d_out;

    // Zero all output bytes with the rocclr fill kernel (proven 6.7 TB/s
    // store-issue rate on this buffer). 0x00 bytes == 0.0f bitwise.
    hipMemsetAsync(d_out, 0, (size_t)out_size, stream);

    bow_sparse_half_kernel<<<dim3(BATCH * 2), dim3(BLOCK), 0, stream>>>(
        tokens, out);
}

// Round 10
// 194.731 us; speedup vs baseline: 1.1161x; 1.1161x over previous
//
#include <hip/hip_runtime.h>

// BagOfWords: input [1024, 512] int32 tokens in [0, 50257).
// Output [1024, 50256] float32: per-row histogram, vocab bin 0 dropped.
//
// FINAL (restore of R5/R8-design mask-gated streaming kernel, best measured
// at 194.9 us). Session conclusion:
//
//   dur_us ~= 123 us harness poison fill (823 MB @ 6.7 TB/s, fixed)
//           + ~35-40 us fixed per-iteration harness overhead
//           + ~35 us this kernel (205.8 MB mandatory output stores
//             / 6.7 TB/s demonstrated store-issue ceiling = 30.7 us floor
//             + ~4 us amortized block lifecycle).
//
// Evidence: six structurally independent designs (fused readback / global
// atomic scatter / memset+plain scatter / mask-gated stream / wide-chunk /
// persistent half-row) all measured 195-201 on clean windows -- design-space
// spread == window noise. Substituting the literal rocclr fill kernel via
// hipMemsetAsync for our zero phase REGRESSED reproducibly (217.1 / 217.3,
// two windows) -> our in-kernel zero+sparse path is at least as fast as the
// platform's own peak-rate fill; kernel-side time is within ~15% of the
// mandatory-write floor. Remaining dur_us is harness reset cost.
//
// Design: one block per (row, 4096-col chunk), 13x1024 blocks, 20 KB LDS
// (8 blocks/CU, 32 waves). Atomic phase marks occupied 4-bin groups in a
// 4 KB mask. Store phase: common path (mask==0, ~99%) stores a constant
// zero -- no LDS dependency, back-to-back float4 stores; rare path reads
// hist. Every output dword written exactly once -> no vmcnt drain. Raw
// lgkm-only barriers (no __syncthreads vmcnt(0) drain). Plain stores, NOT
// nontemporal (nt bypasses MALL absorption, +10 us).

#define BATCH 1024
#define SEQ 512
#define VOCAB 50257
#define OUT_COLS (VOCAB - 1)   // 50256
#define CHUNK 4096
#define NGROUP (CHUNK / 4)     // 1024 mask groups of 4 bins
#define NBLK_PER_ROW 13        // 12 full + 1104-col tail
#define BLOCK 256

// LDS-only barrier: waits ds ops (lgkmcnt) but does NOT drain global stores
// (__syncthreads would emit s_waitcnt vmcnt(0) and stall the store pipe).
#define LDS_BAR()                                              \
    do {                                                       \
        asm volatile("s_waitcnt lgkmcnt(0)" ::: "memory");     \
        __builtin_amdgcn_s_barrier();                          \
        asm volatile("" ::: "memory");                         \
    } while (0)

__global__ __launch_bounds__(BLOCK) void bow_maskstream_kernel(
    const int* __restrict__ tokens, float* __restrict__ out) {
    __shared__ unsigned int hist[CHUNK];   // 16 KB
    __shared__ unsigned int mask[NGROUP];  // 4 KB

    const int t  = threadIdx.x;
    const int c0 = blockIdx.x * CHUNK;
    const int b  = blockIdx.y;

    // Issue the token load first; its wait lands after LDS zeroing + barrier.
    const int2 tk = ((const int2*)(tokens + (size_t)b * SEQ))[t];

    // Zero hist (4x uint4/thread) and mask (1x uint4/thread).
    const uint4 z4 = make_uint4(0u, 0u, 0u, 0u);
    #pragma unroll
    for (int k = 0; k < 4; ++k)
        *(uint4*)&hist[t * 4 + k * (BLOCK * 4)] = z4;
    *(uint4*)&mask[t * 4] = z4;

    LDS_BAR();

    // Histogram + mark occupied 4-bin groups. tok==0 dropped via unsigned
    // underflow (tok-1-c0 wraps huge). Mask write races are benign (all 1u).
    unsigned int r;
    r = (unsigned int)(tk.x - 1 - c0);
    if (r < CHUNK) { atomicAdd(&hist[r], 1u); mask[r >> 2] = 1u; }
    r = (unsigned int)(tk.y - 1 - c0);
    if (r < CHUNK) { atomicAdd(&hist[r], 1u); mask[r >> 2] = 1u; }

    LDS_BAR();

    float* orow = out + (size_t)b * OUT_COLS + c0;
    const int ncols = (c0 + CHUNK <= OUT_COLS) ? CHUNK : (OUT_COLS - c0);

    // Batch the 4 mask-word reads (one lgkm wait), then stream stores.
    // Group g = t + 256k covers bins [4g, 4g+4); per-k store addresses are
    // lane-contiguous (1 KB per wave instruction).
    unsigned int m[4];
    #pragma unroll
    for (int k = 0; k < 4; ++k)
        m[k] = mask[t + k * BLOCK];

    #pragma unroll
    for (int k = 0; k < 4; ++k) {
        const int base = t * 4 + k * (BLOCK * 4);  // = 4 * group
        if (base < ncols) {                        // tail chunk: 1104 cols
            if (m[k] == 0u) {
                *(float4*)(orow + base) = make_float4(0.f, 0.f, 0.f, 0.f);
            } else {
                const uint4 h = *(const uint4*)&hist[base];
                *(float4*)(orow + base) = make_float4(
                    (float)h.x, (float)h.y, (float)h.z, (float)h.w);
            }
        }
    }
}

extern "C" void kernel_launch(void* const* d_in, const int* in_sizes, int n_in,
                              void* d_out, int out_size, void* d_ws, size_t ws_size,
                              hipStream_t stream) {
    const int* tokens = (const int*)d_in[0];
    float* out = (float*)d_out;

    bow_maskstream_kernel<<<dim3(NBLK_PER_ROW, BATCH), dim3(BLOCK), 0, stream>>>(
        tokens, out);
}